// Round 9
// baseline (50176.630 us; speedup 1.0000x reference)
//
#include <hip/hip_runtime.h>

// R9: MEASUREMENT ROUND. Real pipeline is byte-identical to R8 (passes).
// Three microbench kernels sized so their duration exceeds lstm_seq's 12.7ms
// replicas whenever their measured quantity matters (the top-5 per-dispatch
// table is the read-back channel):
//   mb_clock   : 12.58M serial dep FMAs (~50.3M cy) -> shader clock.
//   mb_chase   : 15000 serial sc0sc1 dependent loads -> LLC-coherent latency.
//   mb_barrier : 6000 iterations of R8's exact flag barrier -> barrier cost.
// Decision tree in the round notes.

typedef unsigned short u16;
typedef unsigned int u32;
typedef __attribute__((ext_vector_type(8))) short bf16x8;
typedef __attribute__((ext_vector_type(4))) float f32x4;

#define NBLK 64
#define SEQ 512
#define BATCH 64
#define HID 1024
#define KDIM 2048
#define NGATES 4096
#define GB_STRIDE 68
#define XS_STRIDE 1032                 // 1024 + 8 pad
#define SMEM_PP (64 * XS_STRIDE * 2)   // prepass LDS: 132096 B
#define FLAG_STRIDE 64                 // u32s between flags = 256 B/line

__device__ __forceinline__ u16 f2bf(float f) {
  u32 u = __builtin_bit_cast(u32, f);
  u += 0x7FFFu + ((u >> 16) & 1u);   // RNE
  return (u16)(u >> 16);
}
__device__ __forceinline__ float bf2f(u32 v) {
  return __builtin_bit_cast(float, v << 16);
}

// ---- LLC-coherent primitives (sc0 sc1 = device-coherent, bypass L1/L2) ----
__device__ __forceinline__ void llc_store_u16(u16* p, u16 v) {
  asm volatile("global_store_short %0, %1, off sc0 sc1" :: "v"(p), "v"((u32)v) : "memory");
}
__device__ __forceinline__ void llc_store_u32(u32* p, u32 v) {
  asm volatile("global_store_dword %0, %1, off sc0 sc1" :: "v"(p), "v"(v) : "memory");
}
__device__ __forceinline__ u32 llc_load_u32(const u32* p) {
  u32 r;
  asm volatile("global_load_dword %0, %1, off sc0 sc1\n\ts_waitcnt vmcnt(0)"
               : "=v"(r) : "v"(p) : "memory");
  return r;
}
#define LLC_LOAD8(dst, ap)                                                   \
  asm volatile("global_load_dwordx4 %0, %8, off sc0 sc1\n\t"                 \
               "global_load_dwordx4 %1, %8, off offset:64 sc0 sc1\n\t"       \
               "global_load_dwordx4 %2, %8, off offset:128 sc0 sc1\n\t"      \
               "global_load_dwordx4 %3, %8, off offset:192 sc0 sc1\n\t"      \
               "global_load_dwordx4 %4, %8, off offset:256 sc0 sc1\n\t"      \
               "global_load_dwordx4 %5, %8, off offset:320 sc0 sc1\n\t"      \
               "global_load_dwordx4 %6, %8, off offset:384 sc0 sc1\n\t"      \
               "global_load_dwordx4 %7, %8, off offset:448 sc0 sc1"          \
               : "=&v"(dst[0]), "=&v"(dst[1]), "=&v"(dst[2]), "=&v"(dst[3]), \
                 "=&v"(dst[4]), "=&v"(dst[5]), "=&v"(dst[6]), "=&v"(dst[7])  \
               : "v"(ap))

// ---------- prep: W transpose+bf16; zero BOTH flag regions; init chase ring ----------
__global__ void prep_w(const float* __restrict__ W, u16* __restrict__ Wt,
                       u32* __restrict__ bar) {
  __shared__ float tile[64][65];
  const int kb = blockIdx.x * 64;
  const int nb = blockIdx.y * 64;
  const int tx = threadIdx.x & 63;
  const int ty = threadIdx.x >> 6;
  for (int r = ty; r < 64; r += 4)
    tile[r][tx] = W[(size_t)(kb + r) * NGATES + nb + tx];
  __syncthreads();
  for (int r = ty; r < 64; r += 4)
    Wt[(size_t)(nb + r) * KDIM + kb + tx] = f2bf(tile[tx][r]);
  if (blockIdx.x == 0 && blockIdx.y == 0) {
    for (int i = threadIdx.x; i < 2 * NBLK * FLAG_STRIDE; i += 256)
      bar[i] = 0;                                    // bar (lstm) + bar2 (mb)
    u32* ring = bar + 2 * NBLK * FLAG_STRIDE;
    for (int i = threadIdx.x; i < 64; i += 256)
      ring[i * 64] = (u32)((i + 37) & 63);           // full-cycle permutation
  }
}

// ---------- prep: x f32 -> bf16 ----------
__global__ void prep_x(const float* __restrict__ x, u16* __restrict__ xb) {
  const size_t n4 = (size_t)SEQ * BATCH * HID / 4;
  size_t i = (size_t)blockIdx.x * blockDim.x + threadIdx.x;
  const size_t stride = (size_t)gridDim.x * blockDim.x;
  for (; i < n4; i += stride) {
    const float4 v = *(const float4*)(x + i * 4);
    u32 lo = (u32)f2bf(v.x) | ((u32)f2bf(v.y) << 16);
    u32 hi = (u32)f2bf(v.z) | ((u32)f2bf(v.w) << 16);
    *(uint2*)(xb + i * 4) = make_uint2(lo, hi);
  }
}

// ---------- prepass: gxF[bid][t][g][c16][row64] bf16 = (x_t @ Wx) fragments ----------
__global__ __launch_bounds__(512) void prepass_gx(
    const u16* __restrict__ xb, const u16* __restrict__ Wt, u16* __restrict__ gxF)
{
  extern __shared__ u16 xs[];     // [64][XS_STRIDE]
  const int tid = threadIdx.x;
  const int lane = tid & 63;
  const int wv = tid >> 6;
  const int col16 = lane & 15;
  const int kg = lane >> 4;
  const int t0 = blockIdx.x * 2;

  for (int tp = 0; tp < 2; ++tp) {
    const int t = t0 + tp;
    if (tp) __syncthreads();
    const u16* xsrc = xb + (size_t)t * (BATCH * HID);
    #pragma unroll
    for (int it = 0; it < 16; ++it) {
      const int flat = it * 512 + tid;
      const int row = flat >> 7, k0 = (flat & 127) * 8;
      *(bf16x8*)(xs + row * XS_STRIDE + k0) = *(const bf16x8*)(xsrc + row * HID + k0);
    }
    __syncthreads();
    const int g = wv >> 1;
    for (int nt = 0; nt < 32; ++nt) {
      const int col = wv * 512 + nt * 16 + col16;
      const u16* bp = Wt + (size_t)col * KDIM + HID + kg * 8;
      f32x4 acc[4];
      #pragma unroll
      for (int mt = 0; mt < 4; ++mt) acc[mt] = (f32x4){0.f, 0.f, 0.f, 0.f};
      #pragma unroll 4
      for (int kt = 0; kt < 32; ++kt) {
        const bf16x8 bw = *(const bf16x8*)(bp + kt * 32);
        #pragma unroll
        for (int mt = 0; mt < 4; ++mt) {
          const bf16x8 av = *(const bf16x8*)(xs + (mt * 16 + col16) * XS_STRIDE
                                                + kt * 32 + kg * 8);
          acc[mt] = __builtin_amdgcn_mfma_f32_16x16x32_bf16(av, bw, acc[mt], 0, 0, 0);
        }
      }
      const int bid16 = (wv & 1) * 32 + nt;
      #pragma unroll
      for (int mt = 0; mt < 4; ++mt) {
        u16* dst = gxF + ((((size_t)bid16 * SEQ + t) * 4 + g) * 16 + col16) * 64
                       + mt * 16 + kg * 4;
        const u32 lo = (u32)f2bf(acc[mt][0]) | ((u32)f2bf(acc[mt][1]) << 16);
        const u32 hi = (u32)f2bf(acc[mt][2]) | ((u32)f2bf(acc[mt][3]) << 16);
        *(uint2*)dst = make_uint2(lo, hi);
      }
    }
  }
}

// ---------- sequential LSTM: BYTE-IDENTICAL to R8 ----------
__global__ __launch_bounds__(512) void lstm_seq(
    const float* __restrict__ bias, const float* __restrict__ h0,
    const float* __restrict__ c0, const u16* __restrict__ Wt,
    const u16* __restrict__ gxF, u16* __restrict__ hbuf,
    float* __restrict__ out, u32* __restrict__ bar)
{
  __shared__ float gb[64 * GB_STRIDE];
  const int tid = threadIdx.x;
  const int bid = blockIdx.x;
  const int lane = tid & 63;
  const int wave = tid >> 6;
  const int nh = wave & 1;
  const int kq = wave >> 1;
  const int col16 = lane & 15;
  const int kg = lane >> 4;

  bf16x8 wh[8][2];
  #pragma unroll
  for (int kt = 0; kt < 8; ++kt)
    #pragma unroll
    for (int nt = 0; nt < 2; ++nt) {
      const int g = nh * 2 + nt;
      wh[kt][nt] = *(const bf16x8*)(Wt + (size_t)(g * HID + bid * 16 + col16) * KDIM
                                       + kq * 256 + kt * 32 + kg * 8);
    }
  const float bv0 = bias[(nh * 2 + 0) * HID + bid * 16 + col16];
  const float bv1 = bias[(nh * 2 + 1) * HID + bid * 16 + col16];

  const int r0 = tid >> 4;
  const int colg = bid * 16 + (tid & 15);
  float cst0 = c0[colg], cst1 = cst0;
  {
    const u16 h0b = f2bf(h0[colg]);
    llc_store_u16(hbuf + (size_t)r0 * HID + colg, h0b);
    llc_store_u16(hbuf + (size_t)(r0 + 32) * HID + colg, h0b);
  }
  __syncthreads();
  if (tid == 0) llc_store_u32(bar + bid * FLAG_STRIDE, 1u);

  uint2 gxr[8];
  auto gxload = [&](int t) {
    if (kq == 0) {
      const u16* sb = gxF + ((size_t)bid * SEQ + t) * 4096;
      #pragma unroll
      for (int mt = 0; mt < 4; ++mt)
        #pragma unroll
        for (int nt = 0; nt < 2; ++nt)
          gxr[mt * 2 + nt] = *(const uint2*)(sb + ((nh * 2 + nt) * 16 + col16) * 64
                                                + mt * 16 + kg * 4);
    }
  };
  gxload(0);

  f32x4 acc[4][2];
  const size_t aoff = (size_t)col16 * HID + kq * 256 + kg * 8;

  for (int t = 0; t < SEQ; ++t) {
    const u32 gen = (u32)t + 1;
    if (tid < NBLK) {
      for (;;) {
        const u32 fl = llc_load_u32(bar + tid * FLAG_STRIDE);
        if (fl >= gen) break;
        __builtin_amdgcn_s_sleep(8);
      }
    }
    __syncthreads();

    #pragma unroll
    for (int mt = 0; mt < 4; ++mt) {
      acc[mt][0] = (f32x4){0.f, 0.f, 0.f, 0.f};
      acc[mt][1] = (f32x4){0.f, 0.f, 0.f, 0.f};
    }
    const u16* hbase = hbuf + (size_t)(t & 1) * (BATCH * HID) + aoff;
    {
      bf16x8 ha[8], hb2[8];
      asm volatile("s_waitcnt vmcnt(0)" ::: "memory");
      LLC_LOAD8(ha, hbase);
      #pragma unroll
      for (int mt = 0; mt < 4; ++mt) {
        if (mt < 3) {
          const u16* hn = hbase + (size_t)(mt + 1) * 16 * HID;
          if (mt & 1) { LLC_LOAD8(ha, hn); } else { LLC_LOAD8(hb2, hn); }
          asm volatile("s_waitcnt vmcnt(8)" ::: "memory");
        } else {
          asm volatile("s_waitcnt vmcnt(0)" ::: "memory");
        }
        __builtin_amdgcn_sched_barrier(0);
        #pragma unroll
        for (int kt = 0; kt < 8; ++kt) {
          const bf16x8 av = (mt & 1) ? hb2[kt] : ha[kt];
          acc[mt][0] = __builtin_amdgcn_mfma_f32_16x16x32_bf16(av, wh[kt][0], acc[mt][0], 0, 0, 0);
          acc[mt][1] = __builtin_amdgcn_mfma_f32_16x16x32_bf16(av, wh[kt][1], acc[mt][1], 0, 0, 0);
        }
      }
    }

    if (kq == 0) {
      #pragma unroll
      for (int mt = 0; mt < 4; ++mt)
        #pragma unroll
        for (int nt = 0; nt < 2; ++nt) {
          const float bv = nt ? bv1 : bv0;
          const uint2 gv = gxr[mt * 2 + nt];
          const float gx0 = bf2f(gv.x & 0xffffu), gx1 = bf2f(gv.x >> 16);
          const float gx2 = bf2f(gv.y & 0xffffu), gx3 = bf2f(gv.y >> 16);
          float* gp = gb + (mt * 16 + kg * 4) * GB_STRIDE + (nh * 2 + nt) * 16 + col16;
          gp[0 * GB_STRIDE] = acc[mt][nt][0] + bv + gx0;
          gp[1 * GB_STRIDE] = acc[mt][nt][1] + bv + gx1;
          gp[2 * GB_STRIDE] = acc[mt][nt][2] + bv + gx2;
          gp[3 * GB_STRIDE] = acc[mt][nt][3] + bv + gx3;
        }
    }
    __syncthreads();
    if (kq != 0) {
      #pragma unroll
      for (int mt = 0; mt < 4; ++mt)
        #pragma unroll
        for (int nt = 0; nt < 2; ++nt)
          #pragma unroll
          for (int r = 0; r < 4; ++r)
            atomicAdd(&gb[(mt * 16 + kg * 4 + r) * GB_STRIDE + (nh * 2 + nt) * 16 + col16],
                      acc[mt][nt][r]);
    }
    __syncthreads();

    u16* hw = hbuf + (size_t)((t + 1) & 1) * (BATCH * HID);
    const int cl = tid & 15;
    #pragma unroll
    for (int cc = 0; cc < 2; ++cc) {
      const int row = r0 + cc * 32;
      const float vf = gb[row * GB_STRIDE + cl];
      const float vi = gb[row * GB_STRIDE + 16 + cl];
      const float vg = gb[row * GB_STRIDE + 32 + cl];
      const float vo = gb[row * GB_STRIDE + 48 + cl];
      const float ft = 1.f / (1.f + __expf(-vf));
      const float it = 1.f / (1.f + __expf(-vi));
      const float eg = __expf(2.f * vg);
      const float gt = 1.f - 2.f / (eg + 1.f);
      const float ot = 1.f / (1.f + __expf(-vo));
      const float cold = cc ? cst1 : cst0;
      const float cn = ft * cold + it * gt;
      const float ec = __expf(2.f * cn);
      const float th = 1.f - 2.f / (ec + 1.f);
      const float hn = ot * th;
      if (cc) cst1 = cn; else cst0 = cn;
      llc_store_u16(hw + (size_t)row * HID + colg, f2bf(hn));
      if (t == SEQ - 1) {
        out[(size_t)row * HID + colg] = hn;
        out[(size_t)BATCH * HID + (size_t)row * HID + colg] = cn;
      }
    }
    __syncthreads();

    if (t < SEQ - 1) {
      if (tid == 0) llc_store_u32(bar + bid * FLAG_STRIDE, gen + 1);
      gxload(t + 1);
    }
  }
}

// ---------- mb_clock: 12.58M serial dependent FMAs (~50.3M cy @4cy) ----------
__global__ void mb_clock() {
  float f = 1.0f + threadIdx.x * 1e-7f;
  for (u32 i = 0; i < 196608u; ++i) {
    #pragma unroll
    for (int j = 0; j < 64; ++j)
      f = __builtin_fmaf(f, 1.0000001f, 1e-9f);
  }
  asm volatile("" :: "v"(f));
}

// ---------- mb_chase: 15000 serial sc0sc1 dependent loads (MALL-resident ring) ----------
__global__ void mb_chase(u32* ring) {
  if (threadIdx.x == 0 && blockIdx.x == 0) {
    u32 v = 0;
    for (int i = 0; i < 15000; ++i)
      v = llc_load_u32(ring + (size_t)(v & 63) * 64);
    asm volatile("" :: "v"(v));
  }
}

// ---------- mb_barrier: 6000 iterations of R8's exact flag barrier ----------
__global__ __launch_bounds__(512) void mb_barrier(u32* bar2) {
  __shared__ u32 pad[4352];              // match lstm_seq's 17408B LDS footprint
  const int tid = threadIdx.x;
  const int bid = blockIdx.x;
  pad[tid] = tid;
  __syncthreads();
  for (u32 gen = 1; gen <= 6000u; ++gen) {
    if (tid == 0) llc_store_u32(bar2 + bid * FLAG_STRIDE, gen);
    if (tid < NBLK) {
      u32 guard = 0;
      while (llc_load_u32(bar2 + tid * FLAG_STRIDE) < gen && ++guard < (1u << 22))
        __builtin_amdgcn_s_sleep(8);
    }
    __syncthreads();
  }
  asm volatile("" :: "v"(((volatile u32*)pad)[tid & 4095]));
}

extern "C" void kernel_launch(void* const* d_in, const int* in_sizes, int n_in,
                              void* d_out, int out_size, void* d_ws, size_t ws_size,
                              hipStream_t stream) {
  const float* x    = (const float*)d_in[0];
  const float* W    = (const float*)d_in[1];
  const float* bias = (const float*)d_in[2];
  const float* h0   = (const float*)d_in[3];
  const float* c0   = (const float*)d_in[4];
  float* out = (float*)d_out;

  char* w = (char*)d_ws;
  u16* Wt   = (u16*)w;                                        // 16 MB
  u16* xbq  = (u16*)(w + ((size_t)16 << 20));                 // 64 MB
  u16* hbuf = (u16*)(w + ((size_t)80 << 20));                 // 256 KB
  u32* bar  = (u32*)(w + ((size_t)80 << 20) + (512 << 10));   // 16K lstm flags
  u32* bar2 = bar + NBLK * FLAG_STRIDE;                       // 16K mb flags
  u32* ring = bar + 2 * NBLK * FLAG_STRIDE;                   // 16K chase ring
  u16* gxF  = (u16*)(w + ((size_t)81 << 20));                 // 256 MB
  const size_t need = ((size_t)81 << 20) + ((size_t)256 << 20);
  if (ws_size < need) return;

  (void)hipFuncSetAttribute((const void*)prepass_gx,
                            hipFuncAttributeMaxDynamicSharedMemorySize, SMEM_PP);

  hipLaunchKernelGGL(prep_w, dim3(32, 64), dim3(256), 0, stream, W, Wt, bar);
  hipLaunchKernelGGL(prep_x, dim3(4096), dim3(256), 0, stream, x, xbq);
  hipLaunchKernelGGL(prepass_gx, dim3(256), dim3(512), SMEM_PP, stream, xbq, Wt, gxF);
  hipLaunchKernelGGL(lstm_seq, dim3(NBLK), dim3(512), 0, stream,
                     bias, h0, c0, Wt, gxF, hbuf, out, bar);
  // ---- diagnostics (read via per-dispatch durations in the profile) ----
  hipLaunchKernelGGL(mb_clock, dim3(1), dim3(64), 0, stream);
  hipLaunchKernelGGL(mb_chase, dim3(1), dim3(64), 0, stream, ring);
  hipLaunchKernelGGL(mb_barrier, dim3(NBLK), dim3(512), 0, stream, bar2);
}

// Round 10
// 18137.216 us; speedup vs baseline: 2.7665x; 2.7665x over previous
//
#include <hip/hip_runtime.h>

// R10: two-level h exchange. R9 measured: clock 2.27GHz (DVFS dead), flag
// barrier <=2.5us/iter, sc0sc1 hop <=1us -- so the ~25us/step is the 8MB/step
// of uncached (sc0sc1) h reads (64 blocks x full 128KB h) at low MALL-bypass
// BW. Fix: each block uncached-reads ONE 16KB slice (1MB/step aggregate, 8x
// cut), re-stores it CACHED into an XCD-local buffer (runtime XCC_ID + ticket
// rank; slice flags through the same L2 -> wrong mapping shows as timeout ->
// bounded-spin fallback to the proven direct-MALL path). Consumers read h as
// L2 hits (sc0). Wh moved to LDS (one-time), ending the per-step L2 restream
// (VGPR=104 proved it never stayed in registers).

typedef unsigned short u16;
typedef unsigned int u32;
typedef __attribute__((ext_vector_type(8))) short bf16x8;
typedef __attribute__((ext_vector_type(4))) float f32x4;

#define NBLK 64
#define SEQ 512
#define BATCH 64
#define HID 1024
#define KDIM 2048
#define NGATES 4096
#define GB_STRIDE 68
#define XS_STRIDE 1032
#define SMEM_PP (64 * XS_STRIDE * 2)       // prepass LDS
#define FLAG_STRIDE 64                     // u32s between global flags (256B)
#define WH_BYTES 131072                    // Wh in LDS
#define SMEM_SEQ (WH_BYTES + 64 * GB_STRIDE * 4 + 16)
#define SPIN_CAP 8192                      // sf-poll timeout -> fallback

__device__ __forceinline__ u16 f2bf(float f) {
  u32 u = __builtin_bit_cast(u32, f);
  u += 0x7FFFu + ((u >> 16) & 1u);   // RNE
  return (u16)(u >> 16);
}
__device__ __forceinline__ float bf2f(u32 v) {
  return __builtin_bit_cast(float, v << 16);
}

// ---- MALL-coherent (sc0 sc1: bypass L1+L2) ----
__device__ __forceinline__ void llc_store_u16(u16* p, u16 v) {
  asm volatile("global_store_short %0, %1, off sc0 sc1" :: "v"(p), "v"((u32)v) : "memory");
}
__device__ __forceinline__ void llc_store_u32(u32* p, u32 v) {
  asm volatile("global_store_dword %0, %1, off sc0 sc1" :: "v"(p), "v"(v) : "memory");
}
__device__ __forceinline__ u32 llc_load_u32(const u32* p) {
  u32 r;
  asm volatile("global_load_dword %0, %1, off sc0 sc1\n\ts_waitcnt vmcnt(0)"
               : "=v"(r) : "v"(p) : "memory");
  return r;
}
// ---- L2-coherent (sc0: bypass L1, hit local L2) ----
__device__ __forceinline__ void l2_store_u32(u32* p, u32 v) {
  asm volatile("global_store_dword %0, %1, off" :: "v"(p), "v"(v) : "memory");
}
__device__ __forceinline__ u32 l2_load_u32(const u32* p) {
  u32 r;
  asm volatile("global_load_dword %0, %1, off sc0\n\ts_waitcnt vmcnt(0)"
               : "=v"(r) : "v"(p) : "memory");
  return r;
}
#define LLC_LOAD8(dst, ap)                                                   \
  asm volatile("global_load_dwordx4 %0, %8, off sc0 sc1\n\t"                 \
               "global_load_dwordx4 %1, %8, off offset:64 sc0 sc1\n\t"       \
               "global_load_dwordx4 %2, %8, off offset:128 sc0 sc1\n\t"      \
               "global_load_dwordx4 %3, %8, off offset:192 sc0 sc1\n\t"      \
               "global_load_dwordx4 %4, %8, off offset:256 sc0 sc1\n\t"      \
               "global_load_dwordx4 %5, %8, off offset:320 sc0 sc1\n\t"      \
               "global_load_dwordx4 %6, %8, off offset:384 sc0 sc1\n\t"      \
               "global_load_dwordx4 %7, %8, off offset:448 sc0 sc1"          \
               : "=&v"(dst[0]), "=&v"(dst[1]), "=&v"(dst[2]), "=&v"(dst[3]), \
                 "=&v"(dst[4]), "=&v"(dst[5]), "=&v"(dst[6]), "=&v"(dst[7])  \
               : "v"(ap))
#define XCD_LOAD8(dst, ap)                                                   \
  asm volatile("global_load_dwordx4 %0, %8, off sc0\n\t"                     \
               "global_load_dwordx4 %1, %8, off offset:64 sc0\n\t"           \
               "global_load_dwordx4 %2, %8, off offset:128 sc0\n\t"          \
               "global_load_dwordx4 %3, %8, off offset:192 sc0\n\t"          \
               "global_load_dwordx4 %4, %8, off offset:256 sc0\n\t"          \
               "global_load_dwordx4 %5, %8, off offset:320 sc0\n\t"          \
               "global_load_dwordx4 %6, %8, off offset:384 sc0\n\t"          \
               "global_load_dwordx4 %7, %8, off offset:448 sc0"              \
               : "=&v"(dst[0]), "=&v"(dst[1]), "=&v"(dst[2]), "=&v"(dst[3]), \
                 "=&v"(dst[4]), "=&v"(dst[5]), "=&v"(dst[6]), "=&v"(dst[7])  \
               : "v"(ap))
#define LLC_LOAD2(d0, d1, ap)                                                \
  asm volatile("global_load_dwordx4 %0, %2, off sc0 sc1\n\t"                 \
               "global_load_dwordx4 %1, %2, off offset:16 sc0 sc1"           \
               : "=&v"(d0), "=&v"(d1) : "v"(ap))

// ---------- prep: W transpose+bf16; zero bar+tick+sf (contiguous u32 region) ----------
__global__ void prep_w(const float* __restrict__ W, u16* __restrict__ Wt,
                       u32* __restrict__ bar) {
  __shared__ float tile[64][65];
  const int kb = blockIdx.x * 64;
  const int nb = blockIdx.y * 64;
  const int tx = threadIdx.x & 63;
  const int ty = threadIdx.x >> 6;
  for (int r = ty; r < 64; r += 4)
    tile[r][tx] = W[(size_t)(kb + r) * NGATES + nb + tx];
  __syncthreads();
  for (int r = ty; r < 64; r += 4)
    Wt[(size_t)(nb + r) * KDIM + kb + tx] = f2bf(tile[tx][r]);
  if (blockIdx.x == 0 && blockIdx.y == 0)
    for (int i = threadIdx.x; i < NBLK * FLAG_STRIDE + 128 + 1024; i += 256)
      bar[i] = 0;   // bar(4096) + tick(128) + sf(1024)
}

// ---------- prep: x f32 -> bf16 ----------
__global__ void prep_x(const float* __restrict__ x, u16* __restrict__ xb) {
  const size_t n4 = (size_t)SEQ * BATCH * HID / 4;
  size_t i = (size_t)blockIdx.x * blockDim.x + threadIdx.x;
  const size_t stride = (size_t)gridDim.x * blockDim.x;
  for (; i < n4; i += stride) {
    const float4 v = *(const float4*)(x + i * 4);
    u32 lo = (u32)f2bf(v.x) | ((u32)f2bf(v.y) << 16);
    u32 hi = (u32)f2bf(v.z) | ((u32)f2bf(v.w) << 16);
    *(uint2*)(xb + i * 4) = make_uint2(lo, hi);
  }
}

// ---------- prepass: gxF[bid][t][g][c16][row64] bf16 = (x_t @ Wx) fragments ----------
__global__ __launch_bounds__(512) void prepass_gx(
    const u16* __restrict__ xb, const u16* __restrict__ Wt, u16* __restrict__ gxF)
{
  extern __shared__ u16 xs[];
  const int tid = threadIdx.x;
  const int lane = tid & 63;
  const int wv = tid >> 6;
  const int col16 = lane & 15;
  const int kg = lane >> 4;
  const int t0 = blockIdx.x * 2;

  for (int tp = 0; tp < 2; ++tp) {
    const int t = t0 + tp;
    if (tp) __syncthreads();
    const u16* xsrc = xb + (size_t)t * (BATCH * HID);
    #pragma unroll
    for (int it = 0; it < 16; ++it) {
      const int flat = it * 512 + tid;
      const int row = flat >> 7, k0 = (flat & 127) * 8;
      *(bf16x8*)(xs + row * XS_STRIDE + k0) = *(const bf16x8*)(xsrc + row * HID + k0);
    }
    __syncthreads();
    const int g = wv >> 1;
    for (int nt = 0; nt < 32; ++nt) {
      const int col = wv * 512 + nt * 16 + col16;
      const u16* bp = Wt + (size_t)col * KDIM + HID + kg * 8;
      f32x4 acc[4];
      #pragma unroll
      for (int mt = 0; mt < 4; ++mt) acc[mt] = (f32x4){0.f, 0.f, 0.f, 0.f};
      #pragma unroll 4
      for (int kt = 0; kt < 32; ++kt) {
        const bf16x8 bw = *(const bf16x8*)(bp + kt * 32);
        #pragma unroll
        for (int mt = 0; mt < 4; ++mt) {
          const bf16x8 av = *(const bf16x8*)(xs + (mt * 16 + col16) * XS_STRIDE
                                                + kt * 32 + kg * 8);
          acc[mt] = __builtin_amdgcn_mfma_f32_16x16x32_bf16(av, bw, acc[mt], 0, 0, 0);
        }
      }
      const int bid16 = (wv & 1) * 32 + nt;
      #pragma unroll
      for (int mt = 0; mt < 4; ++mt) {
        u16* dst = gxF + ((((size_t)bid16 * SEQ + t) * 4 + g) * 16 + col16) * 64
                       + mt * 16 + kg * 4;
        const u32 lo = (u32)f2bf(acc[mt][0]) | ((u32)f2bf(acc[mt][1]) << 16);
        const u32 hi = (u32)f2bf(acc[mt][2]) | ((u32)f2bf(acc[mt][3]) << 16);
        *(uint2*)dst = make_uint2(lo, hi);
      }
    }
  }
}

// ---------- sequential LSTM with two-level h exchange ----------
__global__ __launch_bounds__(512) void lstm_seq(
    const float* __restrict__ bias, const float* __restrict__ h0,
    const float* __restrict__ c0, const u16* __restrict__ Wt,
    const u16* __restrict__ gxF, u16* __restrict__ hbuf,
    float* __restrict__ out, u32* __restrict__ bar,
    u16* __restrict__ xcdbuf)          // 8 x 128KB XCD-local h copies
{
  extern __shared__ char smem[];
  u16* whl = (u16*)smem;                          // [8 waves][16 frag][64 lane][8] bf16
  float* gb = (float*)(smem + WH_BYTES);
  u32* ctrl = (u32*)(smem + WH_BYTES + 64 * GB_STRIDE * 4);  // [fb, xcc, rank]

  u32* tick = bar + NBLK * FLAG_STRIDE;           // 8 tickets, 64B apart
  u32* sf   = tick + 128;                         // 64 slice flags, 64B apart

  const int tid = threadIdx.x;
  const int bid = blockIdx.x;
  const int lane = tid & 63;
  const int wave = tid >> 6;
  const int nh = wave & 1;
  const int kq = wave >> 1;
  const int col16 = lane & 15;
  const int kg = lane >> 4;

  if (tid == 0) {
    const u32 xcc = __builtin_amdgcn_s_getreg(20 | (31 << 11)) & 7u;  // HW_REG_XCC_ID
    const u32 rank = atomicAdd(tick + xcc * 16, 1u);
    ctrl[0] = 0; ctrl[1] = xcc; ctrl[2] = rank;
  }

  // ---- one-time: Wh (h-half of Wt) -> LDS, fragment order ----
  u16* wb = whl + (size_t)wave * 8192 + (size_t)lane * 8;
  #pragma unroll
  for (int kt = 0; kt < 8; ++kt)
    #pragma unroll
    for (int nt = 0; nt < 2; ++nt) {
      const int g = nh * 2 + nt;
      *(bf16x8*)(wb + (kt * 2 + nt) * 512) =
          *(const bf16x8*)(Wt + (size_t)(g * HID + bid * 16 + col16) * KDIM
                              + kq * 256 + kt * 32 + kg * 8);
    }
  const float bv0 = bias[(nh * 2 + 0) * HID + bid * 16 + col16];
  const float bv1 = bias[(nh * 2 + 1) * HID + bid * 16 + col16];

  const int r0 = tid >> 4;
  const int colg = bid * 16 + (tid & 15);
  float cst0 = c0[colg], cst1 = cst0;
  {
    const u16 h0b = f2bf(h0[colg]);
    llc_store_u16(hbuf + (size_t)r0 * HID + colg, h0b);
    llc_store_u16(hbuf + (size_t)(r0 + 32) * HID + colg, h0b);
  }
  __syncthreads();   // wh LDS ready + h0 at MALL + ctrl ready
  if (tid == 0) llc_store_u32(bar + bid * FLAG_STRIDE, 1u);

  const u32 xcc = ctrl[1];
  const u32 rank = ctrl[2];
  u16* xcb = xcdbuf + (size_t)xcc * 65536;
  int fbreg = 0;

  uint2 gxr[8];
  auto gxload = [&](int t) {
    if (kq == 0) {
      const u16* sb = gxF + ((size_t)bid * SEQ + t) * 4096;
      #pragma unroll
      for (int mt = 0; mt < 4; ++mt)
        #pragma unroll
        for (int nt = 0; nt < 2; ++nt)
          gxr[mt * 2 + nt] = *(const uint2*)(sb + ((nh * 2 + nt) * 16 + col16) * 64
                                                + mt * 16 + kg * 4);
    }
  };
  gxload(0);

  f32x4 acc[4][2];
  const size_t aoff = (size_t)col16 * HID + kq * 256 + kg * 8;

  for (int t = 0; t < SEQ; ++t) {
    const u32 gen = (u32)t + 1;
    // ---- A. global barrier (proven <=2.5us): wave0 polls 64 flags ----
    if (tid < NBLK) {
      for (;;) {
        const u32 fl = llc_load_u32(bar + tid * FLAG_STRIDE);
        if (fl >= gen) break;
        __builtin_amdgcn_s_sleep(8);
      }
    }
    __syncthreads();

    // ---- B. stage my 16KB slice (rows rank*8..+7) MALL -> XCD L2 ----
    if (rank < 8) {
      const u16* src = hbuf + (size_t)(t & 1) * 65536 + rank * 8192 + tid * 16;
      uint4 d0, d1;
      LLC_LOAD2(d0, d1, src);
      asm volatile("s_waitcnt vmcnt(0)" ::: "memory");
      uint4* dst = (uint4*)(xcb + rank * 8192 + tid * 16);
      dst[0] = d0; dst[1] = d1;            // plain: write-through L1 -> local L2
    }
    __syncthreads();                        // stagers' stores acked in L2
    if (rank < 8 && tid == 0) l2_store_u32(sf + (xcc * 8 + rank) * 16, gen);

    // ---- C. wait all 8 slices of my XCD (L2 flags); timeout -> fallback ----
    if (!fbreg && tid < 8) {
      u32 spins = 0;
      for (;;) {
        const u32 fl = l2_load_u32(sf + (xcc * 8 + tid) * 16);
        if (fl >= gen) break;
        if (++spins > SPIN_CAP) { ctrl[0] = 1; break; }
        __builtin_amdgcn_s_sleep(2);
      }
    }
    __syncthreads();
    fbreg = (int)ctrl[0];

    // ---- D. h_t @ Wh: A-frags from XCD L2 copy (or MALL fallback) ----
    #pragma unroll
    for (int mt = 0; mt < 4; ++mt) {
      acc[mt][0] = (f32x4){0.f, 0.f, 0.f, 0.f};
      acc[mt][1] = (f32x4){0.f, 0.f, 0.f, 0.f};
    }
    {
      bf16x8 ha[8], hb2[8];
      asm volatile("s_waitcnt vmcnt(0)" ::: "memory");
      if (!fbreg) {
        const u16* hbase = xcb + aoff;
        XCD_LOAD8(ha, hbase);
        #pragma unroll
        for (int mt = 0; mt < 4; ++mt) {
          if (mt < 3) {
            const u16* hn = hbase + (size_t)(mt + 1) * 16 * HID;
            if (mt & 1) { XCD_LOAD8(ha, hn); } else { XCD_LOAD8(hb2, hn); }
            asm volatile("s_waitcnt vmcnt(8)" ::: "memory");
          } else {
            asm volatile("s_waitcnt vmcnt(0)" ::: "memory");
          }
          __builtin_amdgcn_sched_barrier(0);
          #pragma unroll
          for (int kt = 0; kt < 8; ++kt) {
            const bf16x8 av = (mt & 1) ? hb2[kt] : ha[kt];
            const bf16x8 w0 = *(const bf16x8*)(wb + (kt * 2 + 0) * 512);
            const bf16x8 w1 = *(const bf16x8*)(wb + (kt * 2 + 1) * 512);
            acc[mt][0] = __builtin_amdgcn_mfma_f32_16x16x32_bf16(av, w0, acc[mt][0], 0, 0, 0);
            acc[mt][1] = __builtin_amdgcn_mfma_f32_16x16x32_bf16(av, w1, acc[mt][1], 0, 0, 0);
          }
        }
      } else {
        const u16* hbase = hbuf + (size_t)(t & 1) * 65536 + aoff;
        LLC_LOAD8(ha, hbase);
        #pragma unroll
        for (int mt = 0; mt < 4; ++mt) {
          if (mt < 3) {
            const u16* hn = hbase + (size_t)(mt + 1) * 16 * HID;
            if (mt & 1) { LLC_LOAD8(ha, hn); } else { LLC_LOAD8(hb2, hn); }
            asm volatile("s_waitcnt vmcnt(8)" ::: "memory");
          } else {
            asm volatile("s_waitcnt vmcnt(0)" ::: "memory");
          }
          __builtin_amdgcn_sched_barrier(0);
          #pragma unroll
          for (int kt = 0; kt < 8; ++kt) {
            const bf16x8 av = (mt & 1) ? hb2[kt] : ha[kt];
            const bf16x8 w0 = *(const bf16x8*)(wb + (kt * 2 + 0) * 512);
            const bf16x8 w1 = *(const bf16x8*)(wb + (kt * 2 + 1) * 512);
            acc[mt][0] = __builtin_amdgcn_mfma_f32_16x16x32_bf16(av, w0, acc[mt][0], 0, 0, 0);
            acc[mt][1] = __builtin_amdgcn_mfma_f32_16x16x32_bf16(av, w1, acc[mt][1], 0, 0, 0);
          }
        }
      }
    }

    // ---- E. K-reduction in LDS; kq0 seeds with bias + gates_x ----
    if (kq == 0) {
      #pragma unroll
      for (int mt = 0; mt < 4; ++mt)
        #pragma unroll
        for (int nt = 0; nt < 2; ++nt) {
          const float bv = nt ? bv1 : bv0;
          const uint2 gv = gxr[mt * 2 + nt];
          const float gx0 = bf2f(gv.x & 0xffffu), gx1 = bf2f(gv.x >> 16);
          const float gx2 = bf2f(gv.y & 0xffffu), gx3 = bf2f(gv.y >> 16);
          float* gp = gb + (mt * 16 + kg * 4) * GB_STRIDE + (nh * 2 + nt) * 16 + col16;
          gp[0 * GB_STRIDE] = acc[mt][nt][0] + bv + gx0;
          gp[1 * GB_STRIDE] = acc[mt][nt][1] + bv + gx1;
          gp[2 * GB_STRIDE] = acc[mt][nt][2] + bv + gx2;
          gp[3 * GB_STRIDE] = acc[mt][nt][3] + bv + gx3;
        }
    }
    __syncthreads();
    if (kq != 0) {
      #pragma unroll
      for (int mt = 0; mt < 4; ++mt)
        #pragma unroll
        for (int nt = 0; nt < 2; ++nt)
          #pragma unroll
          for (int r = 0; r < 4; ++r)
            atomicAdd(&gb[(mt * 16 + kg * 4 + r) * GB_STRIDE + (nh * 2 + nt) * 16 + col16],
                      acc[mt][nt][r]);
    }
    __syncthreads();

    // ---- F. gates -> nonlinearity -> c,h update ----
    u16* hw = hbuf + (size_t)((t + 1) & 1) * 65536;
    const int cl = tid & 15;
    #pragma unroll
    for (int cc = 0; cc < 2; ++cc) {
      const int row = r0 + cc * 32;
      const float vf = gb[row * GB_STRIDE + cl];
      const float vi = gb[row * GB_STRIDE + 16 + cl];
      const float vg = gb[row * GB_STRIDE + 32 + cl];
      const float vo = gb[row * GB_STRIDE + 48 + cl];
      const float ft = 1.f / (1.f + __expf(-vf));
      const float it = 1.f / (1.f + __expf(-vi));
      const float eg = __expf(2.f * vg);
      const float gt = 1.f - 2.f / (eg + 1.f);
      const float ot = 1.f / (1.f + __expf(-vo));
      const float cold = cc ? cst1 : cst0;
      const float cn = ft * cold + it * gt;
      const float ec = __expf(2.f * cn);
      const float th = 1.f - 2.f / (ec + 1.f);
      const float hn = ot * th;
      if (cc) cst1 = cn; else cst0 = cn;
      llc_store_u16(hw + (size_t)row * HID + colg, f2bf(hn));
      if (t == SEQ - 1) {
        out[(size_t)row * HID + colg] = hn;
        out[(size_t)BATCH * HID + (size_t)row * HID + colg] = cn;
      }
    }
    __syncthreads();

    if (t < SEQ - 1) {
      if (tid == 0) llc_store_u32(bar + bid * FLAG_STRIDE, gen + 1);
      gxload(t + 1);
    }
  }
}

extern "C" void kernel_launch(void* const* d_in, const int* in_sizes, int n_in,
                              void* d_out, int out_size, void* d_ws, size_t ws_size,
                              hipStream_t stream) {
  const float* x    = (const float*)d_in[0];
  const float* W    = (const float*)d_in[1];
  const float* bias = (const float*)d_in[2];
  const float* h0   = (const float*)d_in[3];
  const float* c0   = (const float*)d_in[4];
  float* out = (float*)d_out;

  char* w = (char*)d_ws;
  u16* Wt     = (u16*)w;                                        // 16 MB
  u16* xbq    = (u16*)(w + ((size_t)16 << 20));                 // 64 MB (dead after prepass)
  u16* xcdbuf = xbq;                                            // reuse: 8 x 128KB
  u16* hbuf   = (u16*)(w + ((size_t)80 << 20));                 // 256 KB
  u32* bar    = (u32*)(w + ((size_t)80 << 20) + (512 << 10));   // bar+tick+sf ~21KB
  u16* gxF    = (u16*)(w + ((size_t)81 << 20));                 // 256 MB
  const size_t need = ((size_t)81 << 20) + ((size_t)256 << 20);
  if (ws_size < need) return;

  (void)hipFuncSetAttribute((const void*)prepass_gx,
                            hipFuncAttributeMaxDynamicSharedMemorySize, SMEM_PP);
  (void)hipFuncSetAttribute((const void*)lstm_seq,
                            hipFuncAttributeMaxDynamicSharedMemorySize, SMEM_SEQ);

  hipLaunchKernelGGL(prep_w, dim3(32, 64), dim3(256), 0, stream, W, Wt, bar);
  hipLaunchKernelGGL(prep_x, dim3(4096), dim3(256), 0, stream, x, xbq);
  hipLaunchKernelGGL(prepass_gx, dim3(256), dim3(512), SMEM_PP, stream, xbq, Wt, gxF);
  hipLaunchKernelGGL(lstm_seq, dim3(NBLK), dim3(512), SMEM_SEQ, stream,
                     bias, h0, c0, Wt, gxF, hbuf, out, bar, xcdbuf);
}

// Round 12
// 11079.218 us; speedup vs baseline: 4.5289x; 1.6370x over previous
//
#include <hip/hip_runtime.h>

// R12: R11 (coalesced h exchange through LDS) with the asm-constraint fix:
// ext_vector u32x4 instead of struct uint4 for "v"-bound asm operands.
// Theory: R1-R8's invariant ~20-25us/step = maximally-uncoalesced h exchange
// (A-frag lanes 2KB apart -> 64 lines per instr @16B used; 65536 x 2B stores).
// R9 bounded barrier <=2.5us, sc0sc1 hop <=1us, clock 2.27GHz.

typedef unsigned short u16;
typedef unsigned int u32;
typedef __attribute__((ext_vector_type(8))) short bf16x8;
typedef __attribute__((ext_vector_type(4))) float f32x4;
typedef __attribute__((ext_vector_type(4))) u32 u32x4;

#define NBLK 64
#define SEQ 512
#define BATCH 64
#define HID 1024
#define KDIM 2048
#define NGATES 4096
#define GB_STRIDE 68
#define XS_STRIDE 1032
#define SMEM_PP (64 * XS_STRIDE * 2)
#define FLAG_STRIDE 64                  // u32s between flags (256B/line)
#define HPAD 32                         // pad bytes per 2048B h row in LDS
#define HROW_STRIDE 2080                // 2048 + HPAD
#define H_LDS_BYTES (64 * HROW_STRIDE)  // 133120
#define GB_BYTES (64 * GB_STRIDE * 4)   // 17408
#define HROW_BYTES (64 * 16 * 2)        // 2048
#define SMEM_SEQ (H_LDS_BYTES + GB_BYTES + HROW_BYTES)   // 152576 <= 160K

__device__ __forceinline__ u16 f2bf(float f) {
  u32 u = __builtin_bit_cast(u32, f);
  u += 0x7FFFu + ((u >> 16) & 1u);   // RNE
  return (u16)(u >> 16);
}
__device__ __forceinline__ float bf2f(u32 v) {
  return __builtin_bit_cast(float, v << 16);
}

// ---- MALL-coherent primitives (sc0 sc1: bypass L1+L2) ----
__device__ __forceinline__ void llc_store_u16(u16* p, u16 v) {
  asm volatile("global_store_short %0, %1, off sc0 sc1" :: "v"(p), "v"((u32)v) : "memory");
}
__device__ __forceinline__ void llc_store_u32(u32* p, u32 v) {
  asm volatile("global_store_dword %0, %1, off sc0 sc1" :: "v"(p), "v"(v) : "memory");
}
__device__ __forceinline__ u32 llc_load_u32(const u32* p) {
  u32 r;
  asm volatile("global_load_dword %0, %1, off sc0 sc1\n\ts_waitcnt vmcnt(0)"
               : "=v"(r) : "v"(p) : "memory");
  return r;
}
__device__ __forceinline__ void llc_load_x4(u32x4& d, const void* p) {
  asm volatile("global_load_dwordx4 %0, %1, off sc0 sc1"
               : "=&v"(d) : "v"(p) : "memory");
}
__device__ __forceinline__ void llc_store_x4(void* p, u32x4 v) {
  asm volatile("global_store_dwordx4 %0, %1, off sc0 sc1" :: "v"(p), "v"(v) : "memory");
}

// ---------- prep: W [2048][4096] f32 -> Wt [4096][2048] bf16 (transposed); zero flags ----------
__global__ void prep_w(const float* __restrict__ W, u16* __restrict__ Wt,
                       u32* __restrict__ bar) {
  __shared__ float tile[64][65];
  const int kb = blockIdx.x * 64;
  const int nb = blockIdx.y * 64;
  const int tx = threadIdx.x & 63;
  const int ty = threadIdx.x >> 6;
  for (int r = ty; r < 64; r += 4)
    tile[r][tx] = W[(size_t)(kb + r) * NGATES + nb + tx];
  __syncthreads();
  for (int r = ty; r < 64; r += 4)
    Wt[(size_t)(nb + r) * KDIM + kb + tx] = f2bf(tile[tx][r]);
  if (blockIdx.x == 0 && blockIdx.y == 0)
    for (int i = threadIdx.x; i < NBLK * FLAG_STRIDE; i += 256)
      bar[i] = 0;
}

// ---------- prep: x f32 -> bf16 ----------
__global__ void prep_x(const float* __restrict__ x, u16* __restrict__ xb) {
  const size_t n4 = (size_t)SEQ * BATCH * HID / 4;
  size_t i = (size_t)blockIdx.x * blockDim.x + threadIdx.x;
  const size_t stride = (size_t)gridDim.x * blockDim.x;
  for (; i < n4; i += stride) {
    const float4 v = *(const float4*)(x + i * 4);
    u32 lo = (u32)f2bf(v.x) | ((u32)f2bf(v.y) << 16);
    u32 hi = (u32)f2bf(v.z) | ((u32)f2bf(v.w) << 16);
    *(uint2*)(xb + i * 4) = make_uint2(lo, hi);
  }
}

// ---------- prepass: gxF[bid][t][g][c16][row64] bf16 = (x_t @ Wx) fragments ----------
__global__ __launch_bounds__(512) void prepass_gx(
    const u16* __restrict__ xb, const u16* __restrict__ Wt, u16* __restrict__ gxF)
{
  extern __shared__ u16 xs[];
  const int tid = threadIdx.x;
  const int lane = tid & 63;
  const int wv = tid >> 6;
  const int col16 = lane & 15;
  const int kg = lane >> 4;
  const int t0 = blockIdx.x * 2;

  for (int tp = 0; tp < 2; ++tp) {
    const int t = t0 + tp;
    if (tp) __syncthreads();
    const u16* xsrc = xb + (size_t)t * (BATCH * HID);
    #pragma unroll
    for (int it = 0; it < 16; ++it) {
      const int flat = it * 512 + tid;
      const int row = flat >> 7, k0 = (flat & 127) * 8;
      *(bf16x8*)(xs + row * XS_STRIDE + k0) = *(const bf16x8*)(xsrc + row * HID + k0);
    }
    __syncthreads();
    for (int nt = 0; nt < 32; ++nt) {
      const int col = wv * 512 + nt * 16 + col16;
      const u16* bp = Wt + (size_t)col * KDIM + HID + kg * 8;
      f32x4 acc[4];
      #pragma unroll
      for (int mt = 0; mt < 4; ++mt) acc[mt] = (f32x4){0.f, 0.f, 0.f, 0.f};
      #pragma unroll 4
      for (int kt = 0; kt < 32; ++kt) {
        const bf16x8 bw = *(const bf16x8*)(bp + kt * 32);
        #pragma unroll
        for (int mt = 0; mt < 4; ++mt) {
          const bf16x8 av = *(const bf16x8*)(xs + (mt * 16 + col16) * XS_STRIDE
                                                + kt * 32 + kg * 8);
          acc[mt] = __builtin_amdgcn_mfma_f32_16x16x32_bf16(av, bw, acc[mt], 0, 0, 0);
        }
      }
      const int g = wv >> 1;
      const int bid16 = (wv & 1) * 32 + nt;
      #pragma unroll
      for (int mt = 0; mt < 4; ++mt) {
        u16* dst = gxF + ((((size_t)bid16 * SEQ + t) * 4 + g) * 16 + col16) * 64
                       + mt * 16 + kg * 4;
        const u32 lo = (u32)f2bf(acc[mt][0]) | ((u32)f2bf(acc[mt][1]) << 16);
        const u32 hi = (u32)f2bf(acc[mt][2]) | ((u32)f2bf(acc[mt][3]) << 16);
        *(uint2*)dst = make_uint2(lo, hi);
      }
    }
  }
}

// ---------- sequential LSTM: coalesced h exchange through LDS ----------
__global__ __launch_bounds__(512, 2) void lstm_seq(
    const float* __restrict__ bias, const float* __restrict__ h0,
    const float* __restrict__ c0, const u16* __restrict__ Wt,
    const u16* __restrict__ gxF, u16* __restrict__ hbuf,
    float* __restrict__ out, u32* __restrict__ bar)
{
  extern __shared__ char smem[];
  char* hls  = smem;                                 // padded h copy (133120B)
  float* gb  = (float*)(smem + H_LDS_BYTES);         // gate sums
  u16* hrow  = (u16*)(smem + H_LDS_BYTES + GB_BYTES);// [64][16] next-h gather

  const int tid = threadIdx.x;
  const int bid = blockIdx.x;
  const int lane = tid & 63;
  const int wave = tid >> 6;
  const int nh = wave & 1;
  const int kq = wave >> 1;
  const int col16 = lane & 15;
  const int kg = lane >> 4;

  // ---- Wh fragments: plain cached loads (L2-resident; written once in prep_w) ----
  bf16x8 wh[8][2];
  #pragma unroll
  for (int kt = 0; kt < 8; ++kt)
    #pragma unroll
    for (int nt = 0; nt < 2; ++nt) {
      const int g = nh * 2 + nt;
      wh[kt][nt] = *(const bf16x8*)(Wt + (size_t)(g * HID + bid * 16 + col16) * KDIM
                                       + kq * 256 + kt * 32 + kg * 8);
    }
  const float bv0 = bias[(nh * 2 + 0) * HID + bid * 16 + col16];
  const float bv1 = bias[(nh * 2 + 1) * HID + bid * 16 + col16];

  // ---- per-thread output cells (rows r0, r0+32; col colg); c in regs ----
  const int r0 = tid >> 4;
  const int colg = bid * 16 + (tid & 15);
  float cst0 = c0[colg], cst1 = cst0;
  {
    const u16 h0b = f2bf(h0[colg]);
    llc_store_u16(hbuf + (size_t)r0 * HID + colg, h0b);
    llc_store_u16(hbuf + (size_t)(r0 + 32) * HID + colg, h0b);
  }
  __syncthreads();
  if (tid == 0) llc_store_u32(bar + bid * FLAG_STRIDE, 1u);

  // ---- loop-carried gx prefetch (kq==0 waves; plain cached, fresh each t) ----
  uint2 gxr[8];
  auto gxload = [&](int t) {
    if (kq == 0) {
      const u16* sb = gxF + ((size_t)bid * SEQ + t) * 4096;
      #pragma unroll
      for (int mt = 0; mt < 4; ++mt)
        #pragma unroll
        for (int nt = 0; nt < 2; ++nt)
          gxr[mt * 2 + nt] = *(const uint2*)(sb + ((nh * 2 + nt) * 16 + col16) * 64
                                                + mt * 16 + kg * 4);
    }
  };
  gxload(0);

  f32x4 acc[4][2];

  for (int t = 0; t < SEQ; ++t) {
    const u32 gen = (u32)t + 1;
    // ---- A. barrier: poll 64 flag lines (proven <=2.5us) ----
    if (tid < NBLK) {
      for (;;) {
        const u32 fl = llc_load_u32(bar + tid * FLAG_STRIDE);
        if (fl >= gen) break;
        __builtin_amdgcn_s_sleep(8);
      }
    }
    __syncthreads();

    // ---- B. stage full h -> LDS, coalesced sc0sc1 (1KB/instr per wave) ----
    {
      const char* hsrc = (const char*)hbuf + (size_t)(t & 1) * 131072;
      u32x4 hst[16];
      #pragma unroll
      for (int j = 0; j < 16; ++j)
        llc_load_x4(hst[j], hsrc + (j * 512 + tid) * 16);
      asm volatile("s_waitcnt vmcnt(0)" ::: "memory");
      __builtin_amdgcn_sched_barrier(0);
      #pragma unroll
      for (int j = 0; j < 16; ++j) {
        const int f = (j * 512 + tid) * 16;
        *(u32x4*)(hls + f + (f >> 11) * HPAD) = hst[j];
      }
    }
    __syncthreads();

    // ---- C. h_t @ Wh: A-frags from LDS (balanced banks), B from regs ----
    #pragma unroll
    for (int mt = 0; mt < 4; ++mt) {
      acc[mt][0] = (f32x4){0.f, 0.f, 0.f, 0.f};
      acc[mt][1] = (f32x4){0.f, 0.f, 0.f, 0.f};
    }
    #pragma unroll
    for (int mt = 0; mt < 4; ++mt) {
      const char* rbase = hls + (col16 + mt * 16) * HROW_STRIDE
                              + (kq * 256 + kg * 8) * 2;
      #pragma unroll
      for (int kt = 0; kt < 8; ++kt) {
        const bf16x8 av = *(const bf16x8*)(rbase + kt * 64);
        acc[mt][0] = __builtin_amdgcn_mfma_f32_16x16x32_bf16(av, wh[kt][0], acc[mt][0], 0, 0, 0);
        acc[mt][1] = __builtin_amdgcn_mfma_f32_16x16x32_bf16(av, wh[kt][1], acc[mt][1], 0, 0, 0);
      }
    }

    // ---- D. K-reduction in LDS; kq0 seeds with bias + gates_x ----
    if (kq == 0) {
      #pragma unroll
      for (int mt = 0; mt < 4; ++mt)
        #pragma unroll
        for (int nt = 0; nt < 2; ++nt) {
          const float bv = nt ? bv1 : bv0;
          const uint2 gv = gxr[mt * 2 + nt];
          const float gx0 = bf2f(gv.x & 0xffffu), gx1 = bf2f(gv.x >> 16);
          const float gx2 = bf2f(gv.y & 0xffffu), gx3 = bf2f(gv.y >> 16);
          float* gp = gb + (mt * 16 + kg * 4) * GB_STRIDE + (nh * 2 + nt) * 16 + col16;
          gp[0 * GB_STRIDE] = acc[mt][nt][0] + bv + gx0;
          gp[1 * GB_STRIDE] = acc[mt][nt][1] + bv + gx1;
          gp[2 * GB_STRIDE] = acc[mt][nt][2] + bv + gx2;
          gp[3 * GB_STRIDE] = acc[mt][nt][3] + bv + gx3;
        }
    }
    __syncthreads();
    if (kq != 0) {
      #pragma unroll
      for (int mt = 0; mt < 4; ++mt)
        #pragma unroll
        for (int nt = 0; nt < 2; ++nt)
          #pragma unroll
          for (int r = 0; r < 4; ++r)
            atomicAdd(&gb[(mt * 16 + kg * 4 + r) * GB_STRIDE + (nh * 2 + nt) * 16 + col16],
                      acc[mt][nt][r]);
    }
    __syncthreads();

    // ---- E. gates -> nonlinearity -> c update; next-h into hrow LDS ----
    const int cl = tid & 15;
    #pragma unroll
    for (int cc = 0; cc < 2; ++cc) {
      const int row = r0 + cc * 32;
      const float vf = gb[row * GB_STRIDE + cl];
      const float vi = gb[row * GB_STRIDE + 16 + cl];
      const float vg = gb[row * GB_STRIDE + 32 + cl];
      const float vo = gb[row * GB_STRIDE + 48 + cl];
      const float ft = 1.f / (1.f + __expf(-vf));
      const float it = 1.f / (1.f + __expf(-vi));
      const float eg = __expf(2.f * vg);
      const float gt = 1.f - 2.f / (eg + 1.f);     // tanh
      const float ot = 1.f / (1.f + __expf(-vo));
      const float cold = cc ? cst1 : cst0;
      const float cn = ft * cold + it * gt;
      const float ec = __expf(2.f * cn);
      const float th = 1.f - 2.f / (ec + 1.f);     // tanh
      const float hn = ot * th;
      if (cc) cst1 = cn; else cst0 = cn;
      hrow[row * 16 + cl] = f2bf(hn);
      if (t == SEQ - 1) {
        out[(size_t)row * HID + colg] = hn;
        out[(size_t)BATCH * HID + (size_t)row * HID + colg] = cn;
      }
    }
    __syncthreads();

    // ---- F. emit h slice as 64 x 32B contiguous chunks (2 waves) ----
    if (tid < 128) {
      const int row = tid >> 1, half = tid & 1;
      const u32x4 v = *(const u32x4*)(hrow + row * 16 + half * 8);
      char* dst = (char*)hbuf + (size_t)((t + 1) & 1) * 131072
                + (size_t)row * 2048 + bid * 32 + half * 16;
      llc_store_x4(dst, v);
    }
    __syncthreads();   // per-wave vmcnt drain before flag release

    if (t < SEQ - 1) {
      if (tid == 0) llc_store_u32(bar + bid * FLAG_STRIDE, gen + 1);
      gxload(t + 1);
    }
  }
}

extern "C" void kernel_launch(void* const* d_in, const int* in_sizes, int n_in,
                              void* d_out, int out_size, void* d_ws, size_t ws_size,
                              hipStream_t stream) {
  const float* x    = (const float*)d_in[0];
  const float* W    = (const float*)d_in[1];
  const float* bias = (const float*)d_in[2];
  const float* h0   = (const float*)d_in[3];
  const float* c0   = (const float*)d_in[4];
  float* out = (float*)d_out;

  char* w = (char*)d_ws;
  u16* Wt   = (u16*)w;                                        // 16 MB
  u16* xbq  = (u16*)(w + ((size_t)16 << 20));                 // 64 MB
  u16* hbuf = (u16*)(w + ((size_t)80 << 20));                 // 256 KB
  u32* bar  = (u32*)(w + ((size_t)80 << 20) + (512 << 10));   // 16 KB flags
  u16* gxF  = (u16*)(w + ((size_t)81 << 20));                 // 256 MB
  const size_t need = ((size_t)81 << 20) + ((size_t)256 << 20);
  if (ws_size < need) return;

  (void)hipFuncSetAttribute((const void*)prepass_gx,
                            hipFuncAttributeMaxDynamicSharedMemorySize, SMEM_PP);
  (void)hipFuncSetAttribute((const void*)lstm_seq,
                            hipFuncAttributeMaxDynamicSharedMemorySize, SMEM_SEQ);

  hipLaunchKernelGGL(prep_w, dim3(32, 64), dim3(256), 0, stream, W, Wt, bar);
  hipLaunchKernelGGL(prep_x, dim3(4096), dim3(256), 0, stream, x, xbq);
  hipLaunchKernelGGL(prepass_gx, dim3(256), dim3(512), SMEM_PP, stream, xbq, Wt, gxF);
  hipLaunchKernelGGL(lstm_seq, dim3(NBLK), dim3(512), SMEM_SEQ, stream,
                     bias, h0, c0, Wt, gxF, hbuf, out, bar);
}